// Round 15
// baseline (367.086 us; speedup 1.0000x reference)
//
#include <hip/hip_runtime.h>

// B=2, LQ=LK=2048, D=1024, H=16, DK=DV=64
// Inputs f32 (mask int32); output f32. Internals bf16 MFMA.
// Session: R3 flash 32x32 swapped-QK^T register-P; R5 group-affine XCD
// swizzle (flash 115->89us); R7 prep merge (-13us); R10 proj ring (-26us);
// R11 fc ring (-5us); R12 proj z-swizzle; R14 flash R5-revert (324.6us).
// R15: fc+LN FUSED into fcln_kernel: BM=32 rows x all 1024 cols per block
// (grid 256 = 1/CU, 512 thr). Removes the 64MB preLN round-trip + 1 node.
// LDS 2-slot dbuf (slot = A 2KB + B 64KB), R5-proven full-__syncthreads
// race structure (stage(t+1) after barrier into slot (t-1)&1). Wave w owns
// cols w*128..+128 (acc[2][8]); LN via shfl_xor(ln15) partials ->
// sums[8][32] LDS -> 2 barriers -> mean/var -> scale+write. f32 LN math
// identical to old ln_kernel.

typedef unsigned short u16;
typedef unsigned int   u32;
typedef unsigned long long u64;

typedef __attribute__((ext_vector_type(8))) short frag_ab;   // 8 bf16 (4 VGPRs)
typedef __attribute__((ext_vector_type(4))) float frag_cd;   // 4 f32
typedef __attribute__((ext_vector_type(16))) float f32x16;   // 32x32 acc
typedef __attribute__((ext_vector_type(8))) unsigned short u16x8;
typedef __attribute__((ext_vector_type(4))) unsigned short u16x4;
typedef __attribute__((ext_vector_type(2))) unsigned int u32x2;
typedef __attribute__((ext_vector_type(4))) int int4v;

__device__ __forceinline__ u16 f2bf(float f) {           // RNE
    u32 x = __builtin_bit_cast(u32, f);
    return (u16)((x + 0x7fffu + ((x >> 16) & 1u)) >> 16);
}

// pack two f32 -> {hi:trunc-bf16(b), lo:trunc-bf16(a)} in one v_perm_b32
__device__ __forceinline__ u32 pkbf(float a, float b) {
    return __builtin_amdgcn_perm(__builtin_bit_cast(u32, b),
                                 __builtin_bit_cast(u32, a), 0x07060302u);
}

// async global->LDS, 16 B/lane; LDS dest = wave-uniform base + lane*16
#define GLDS16(gsrc, ldst)                                                     \
    __builtin_amdgcn_global_load_lds(                                          \
        (const __attribute__((address_space(1))) void*)(gsrc),                 \
        (__attribute__((address_space(3))) void*)(ldst), 16, 0, 0)

#define MFMA32(a, b, c) __builtin_amdgcn_mfma_f32_32x32x16_bf16(a, b, c, 0, 0, 0)

// ---------------- merged prep: downcast x4 | weight transpose x4 | mask pack
__global__ __launch_bounds__(256) void prep_kernel(
    const float* __restrict__ in0, const float* __restrict__ in1,
    const float* __restrict__ in2, const float* __restrict__ in3,
    u16* __restrict__ Ab4,
    const float* __restrict__ w_q, const float* __restrict__ w_k,
    const float* __restrict__ w_v, const float* __restrict__ w_fc,
    u16* __restrict__ wqT, u16* __restrict__ wkT,
    u16* __restrict__ wvT, u16* __restrict__ wfcT,
    const int* __restrict__ mask, u64* __restrict__ bits)
{
    __shared__ u16 tile[32][33];
    const int bid = blockIdx.x;
    const int tid = threadIdx.x;
    if (bid < 8192) {                 // ---- downcast 4 tensors f32 -> bf16
        int z = bid >> 11;
        const float* in = z == 0 ? in0 : z == 1 ? in1 : z == 2 ? in2 : in3;
        u16* o = Ab4 + (size_t)z * 4194304;
        size_t i = ((size_t)(bid & 2047) * 256 + tid) * 8;
        float4 f0 = *(const float4*)(in + i);
        float4 f1 = *(const float4*)(in + i + 4);
        u16x8 t;
        t[0] = f2bf(f0.x); t[1] = f2bf(f0.y); t[2] = f2bf(f0.z); t[3] = f2bf(f0.w);
        t[4] = f2bf(f1.x); t[5] = f2bf(f1.y); t[6] = f2bf(f1.z); t[7] = f2bf(f1.w);
        *(u16x8*)(o + i) = t;
    } else if (bid < 12288) {         // ---- weight transpose + downcast
        int t = bid - 8192;
        int z = t >> 10;
        const float* in = z == 0 ? w_q : z == 1 ? w_k : z == 2 ? w_v : w_fc;
        u16* out = z == 0 ? wqT : z == 1 ? wkT : z == 2 ? wvT : wfcT;
        int bx = (t & 31) * 32, by = ((t >> 5) & 31) * 32;
        int tx = tid & 31, ty = tid >> 5;
        for (int i = 0; i < 32; i += 8)
            tile[ty + i][tx] = f2bf(in[(size_t)(by + ty + i) * 1024 + bx + tx]);
        __syncthreads();
        for (int i = 0; i < 32; i += 8)
            out[(size_t)(bx + ty + i) * 1024 + by + tx] = tile[tx][ty + i];
    } else {                          // ---- pack mask to bitmask
        int pb = bid - 12288;
        int wv = tid >> 6, ln = tid & 63;
        long long base = (long long)pb * 2048 + wv * 512;
        for (int j = 0; j < 8; j++) {
            int v = mask[base + j * 64 + ln];
            u64 bl = __ballot(v != 0);
            if (ln == 0) bits[(base >> 6) + j] = bl;
        }
    }
}

// ---------------- 256x256 8-wave GEMM core (R10, proven): K=1024, BK=32 ----
__device__ __forceinline__ void gemm256_core(
    const u16* __restrict__ A, const u16* __restrict__ BT,
    int bm, int bn, u16* ring, frag_cd acc[8][4])
{
    const int tid = threadIdx.x;
    const int wave = tid >> 6, lane = tid & 63;
    const int ln15 = lane & 15, quad = lane >> 4;
    const int wr = wave >> 2, wc = wave & 3;

    auto stage = [&](int t) {          // tile t -> slot t&3
        u16* slot = ring + (t & 3) * 16384;
        size_t col = (size_t)t * 32 + quad * 8;
        for (int s = 0; s < 4; s++) {
            int f = wave * 4 + s;      // 0..31
            if (f < 16)
                GLDS16(&A[(size_t)(bm + f * 16 + ln15) * 1024 + col], slot + f * 512);
            else
                GLDS16(&BT[(size_t)(bn + (f - 16) * 16 + ln15) * 1024 + col],
                       slot + 8192 + (f - 16) * 512);
        }
    };

    stage(0); stage(1); stage(2);      // 12 glds/wave in flight

    for (int t = 0; t < 32; t++) {
        if (t < 30)       asm volatile("s_waitcnt vmcnt(8) lgkmcnt(0)" ::: "memory");
        else if (t == 30) asm volatile("s_waitcnt vmcnt(4) lgkmcnt(0)" ::: "memory");
        else              asm volatile("s_waitcnt vmcnt(0) lgkmcnt(0)" ::: "memory");
        __builtin_amdgcn_s_barrier();
        __builtin_amdgcn_sched_barrier(0);
        if (t < 29) stage(t + 3);      // slot (t-1)&3: all waves' reads drained
        const u16* slot = ring + (t & 3) * 16384;
        const u16* aBase = slot + wr * 8 * 512;
        const u16* bBase = slot + 8192 + wc * 4 * 512;
        frag_ab b[4];
#pragma unroll
        for (int j = 0; j < 4; j++)
            b[j] = *(const frag_ab*)(bBase + j * 512 + lane * 8);
#pragma unroll
        for (int m = 0; m < 8; m++) {
            frag_ab a = *(const frag_ab*)(aBase + m * 512 + lane * 8);
            __builtin_amdgcn_s_setprio(1);
#pragma unroll
            for (int j = 0; j < 4; j++)
                acc[m][j] = __builtin_amdgcn_mfma_f32_16x16x32_bf16(a, b[j], acc[m][j], 0, 0, 0);
            __builtin_amdgcn_s_setprio(0);
        }
    }
}

// ---------------- projections: z=0 Q (scaled by log2e/16), z=1 K, z=2 Vs, z=3 Vo
// R12 z-clustered XCD swizzle: xcd=bid&7 -> z=xcd>>1 (2 XCDs per z),
// bm=(xcd&1)*8+(w>>2), bn=w&3.
__global__ __launch_bounds__(512, 2) void proj_gemm_kernel(
    const u16* __restrict__ Ab4,
    const u16* __restrict__ wqT, const u16* __restrict__ wkT, const u16* __restrict__ wvT,
    u16* __restrict__ Qb, u16* __restrict__ Kb,
    u16* __restrict__ VsT_g, u16* __restrict__ VoT_g)
{
    __shared__ alignas(16) u16 ring[4 * 16384];   // 128 KB
    const int bid = blockIdx.x;        // 256 blocks, 1D
    const int xcd = bid & 7;
    const int w = bid >> 3;            // 0..31
    const int z = xcd >> 1;
    const int bm = ((xcd & 1) * 8 + (w >> 2)) * 256;
    const int bn = (w & 3) * 256;
    const u16* A = Ab4 + (size_t)z * 4194304;
    const u16* BT = z == 0 ? wqT : z == 1 ? wkT : wvT;
    frag_cd acc[8][4] = {};
    gemm256_core(A, BT, bm, bn, ring, acc);

    const int lane = threadIdx.x & 63;
    const int wave = threadIdx.x >> 6;
    const int ln15 = lane & 15, quad = lane >> 4;
    const int wr = wave >> 2, wc = wave & 3;
    if (z < 2) {
        u16* C = z == 0 ? Qb : Kb;   // [4096][1024]
        const float qsc = z == 0 ? 0.09016844f : 1.0f;   // log2(e)/16 folded into Q
        for (int m = 0; m < 8; m++) for (int j = 0; j < 4; j++) {
            int row0 = bm + wr * 128 + m * 16 + quad * 4;
            int col = bn + wc * 64 + j * 16 + ln15;
            for (int r = 0; r < 4; r++)
                C[(size_t)(row0 + r) * 1024 + col] = f2bf(acc[m][j][r] * qsc);
        }
    } else {
        u16* C = z == 2 ? VsT_g : VoT_g;  // [1024][4096] transposed
        for (int m = 0; m < 8; m++) for (int j = 0; j < 4; j++) {
            int row0 = bm + wr * 128 + m * 16 + quad * 4;
            int col = bn + wc * 64 + j * 16 + ln15;
            u16x4 t;
            for (int r = 0; r < 4; r++) t[r] = f2bf(acc[m][j][r]);
            *(u16x4*)&C[(size_t)col * 4096 + row0] = t;
        }
    }
}

// ---------------- fused fc GEMM + residual + LayerNorm -> out --------------
// BM=32 rows x all 1024 cols; grid 256 (1/CU), 512 threads. 2-slot dbuf:
// slot = A 2 frags (2KB) + B 64 frags (64KB). Wave w stages B frags
// w*8..w*8+7 (+ waves 0,1 stage A frags 0,1); full __syncthreads per tile
// (R5 race structure: stage(t+1) after barrier into slot (t-1)&1, whose
// reads drained at the barrier). Wave w computes cols w*128..+128.
__global__ __launch_bounds__(512, 1) void fcln_kernel(
    const u16* __restrict__ Osb, const u16* __restrict__ wfcT,
    const float* __restrict__ resid,
    const float* __restrict__ gamma, const float* __restrict__ beta,
    float* __restrict__ out)
{
    __shared__ alignas(16) u16 ring[2 * 33792];   // 132 KB
    __shared__ float sums[8][32];                  // per-wave row partials
    __shared__ float sums2[8][32];
    const int brow = blockIdx.x * 32;
    const int tid = threadIdx.x;
    const int wave = tid >> 6, lane = tid & 63;
    const int ln15 = lane & 15, quad = lane >> 4;
    const u16* A = Osb;                // Osb||Oob contiguous: M = 8192
    frag_cd acc[2][8] = {};

    auto stage = [&](int t) {          // tile t -> slot t&1
        u16* slot = ring + (t & 1) * 33792;
        size_t col = (size_t)t * 32 + quad * 8;
        for (int s = 0; s < 8; s++) {  // B frags g = wave*8+s (cols g*16+ln15)
            int g = wave * 8 + s;
            GLDS16(&wfcT[(size_t)(g * 16 + ln15) * 1024 + col],
                   slot + 1024 + g * 512);
        }
        if (wave < 2)                  // A frags 0,1 (rows brow + wave*16+ln15)
            GLDS16(&A[(size_t)(brow + wave * 16 + ln15) * 1024 + col],
                   slot + wave * 512);
    };

    stage(0);

    for (int t = 0; t < 32; t++) {
        __syncthreads();               // slot t&1 ready (vmcnt+lgkm drained)
        if (t < 31) stage(t + 1);      // slot (t-1)&1: reads drained at barrier
        const u16* slot = ring + (t & 1) * 33792;
        frag_ab a0 = *(const frag_ab*)(slot + 0 * 512 + lane * 8);
        frag_ab a1 = *(const frag_ab*)(slot + 1 * 512 + lane * 8);
#pragma unroll
        for (int j = 0; j < 8; j++) {
            frag_ab bj = *(const frag_ab*)(slot + 1024 + (wave * 8 + j) * 512 + lane * 8);
            __builtin_amdgcn_s_setprio(1);
            acc[0][j] = __builtin_amdgcn_mfma_f32_16x16x32_bf16(a0, bj, acc[0][j], 0, 0, 0);
            acc[1][j] = __builtin_amdgcn_mfma_f32_16x16x32_bf16(a1, bj, acc[1][j], 0, 0, 0);
            __builtin_amdgcn_s_setprio(0);
        }
    }

    // ---- epilogue: + residual, then row LayerNorm over 1024 cols ----
    // lane's elements: row = m*16 + quad*4 + r, col = wave*128 + j*16 + ln15
#pragma unroll
    for (int m = 0; m < 2; m++)
#pragma unroll
        for (int j = 0; j < 8; j++) {
            int col = wave * 128 + j * 16 + ln15;
#pragma unroll
            for (int r = 0; r < 4; r++) {
                int rowg = brow + m * 16 + quad * 4 + r;
                acc[m][j][r] += resid[(size_t)(rowg & 4095) * 1024 + col];
            }
        }

    // pass 1: row sums -> mean
    float ps[2][4];
#pragma unroll
    for (int m = 0; m < 2; m++)
#pragma unroll
        for (int r = 0; r < 4; r++) {
            float s = 0.f;
#pragma unroll
            for (int j = 0; j < 8; j++) s += acc[m][j][r];
            for (int off = 1; off < 16; off <<= 1) s += __shfl_xor(s, off, 64);
            ps[m][r] = s;              // wave-partial over its 128 cols
        }
    if (ln15 == 0)
        for (int m = 0; m < 2; m++)
            for (int r = 0; r < 4; r++)
                sums[wave][m * 16 + quad * 4 + r] = ps[m][r];
    __syncthreads();
    float mean[2][4];
#pragma unroll
    for (int m = 0; m < 2; m++)
#pragma unroll
        for (int r = 0; r < 4; r++) {
            int row = m * 16 + quad * 4 + r;
            float s = 0.f;
            for (int w = 0; w < 8; w++) s += sums[w][row];
            mean[m][r] = s * (1.0f / 1024.0f);
        }

    // pass 2: variance
#pragma unroll
    for (int m = 0; m < 2; m++)
#pragma unroll
        for (int r = 0; r < 4; r++) {
            float s2 = 0.f;
#pragma unroll
            for (int j = 0; j < 8; j++) {
                float d = acc[m][j][r] - mean[m][r];
                s2 += d * d;
            }
            for (int off = 1; off < 16; off <<= 1) s2 += __shfl_xor(s2, off, 64);
            ps[m][r] = s2;
        }
    if (ln15 == 0)
        for (int m = 0; m < 2; m++)
            for (int r = 0; r < 4; r++)
                sums2[wave][m * 16 + quad * 4 + r] = ps[m][r];
    __syncthreads();

    // load gamma/beta once per col, normalize, write out
    float gg[8], bb[8];
#pragma unroll
    for (int j = 0; j < 8; j++) {
        int col = wave * 128 + j * 16 + ln15;
        gg[j] = gamma[col];
        bb[j] = beta[col];
    }
#pragma unroll
    for (int m = 0; m < 2; m++)
#pragma unroll
        for (int r = 0; r < 4; r++) {
            int row = m * 16 + quad * 4 + r;
            float s2 = 0.f;
            for (int w = 0; w < 8; w++) s2 += sums2[w][row];
            float rstd = rsqrtf(s2 * (1.0f / 1024.0f) + 1e-6f);
            size_t base = (size_t)(brow + row) * 1024;
#pragma unroll
            for (int j = 0; j < 8; j++) {
                int col = wave * 128 + j * 16 + ln15;
                out[base + col] = (acc[m][j][r] - mean[m][r]) * rstd * gg[j] + bb[j];
            }
        }
}

// ---------------- flash (R5, frozen): 32x32, swapped QK^T, register P ------
__device__ __forceinline__ void flash_stage(
    const u16* __restrict__ Kp, const u16* __restrict__ VsT, const u16* __restrict__ VoT,
    int b, int h, int kt, int wave, int ln31, int hi, u16* buf)
{
    const int k0 = kt * 64;
    for (int s = 0; s < 6; s++) {
        int t = wave * 6 + s;          // 0..23
        const u16* g;
        if (t < 8) {                   // K: A-frag rows k = k0+32n+ln31, d-slice ks
            int n = t >> 2, ks = t & 3;
            g = &Kp[(size_t)(b * 2048 + k0 + n * 32 + ln31) * 1024 + h * 64 + ks * 16 + hi * 8];
        } else if (t < 16) {           // Vs^T: B-frag rows d = dt*32+ln31, seq-slice sk
            int dt = (t >> 2) & 1, sk = t & 3;
            g = &VsT[(size_t)(h * 64 + dt * 32 + ln31) * 4096 + b * 2048 + k0 + sk * 16 + hi * 8];
        } else {                       // Vo^T
            int dt = (t >> 2) & 1, sk = t & 3;
            g = &VoT[(size_t)(h * 64 + dt * 32 + ln31) * 4096 + b * 2048 + k0 + sk * 16 + hi * 8];
        }
        GLDS16(g, buf + t * 512);
    }
}

__global__ __launch_bounds__(256, 2) void flash_kernel(
    const u16* __restrict__ Q, const u16* __restrict__ Kp,
    const u16* __restrict__ VsT_g, const u16* __restrict__ VoT_g,
    const float* __restrict__ scores, const u64* __restrict__ mbits,
    u16* __restrict__ Os, u16* __restrict__ Oo)
{
    __shared__ alignas(16) u16 KV[2][24 * 512];   // 48 KB total
    // Group-affine XCD swizzle: all 16 q-tiles of one (b,h) group share one
    // XCD's L2 (4 groups x 768KB = 3MB < 4MB). Bijective for 512 blocks.
    const int bid = blockIdx.x;
    const int xcd = bid & 7;
    const int qt = (bid >> 3) & 15;
    const int g = xcd + 8 * (bid >> 7);    // 0..31
    const int h = g & 15, b = g >> 4;
    const int tid = threadIdx.x;
    const int wave = tid >> 6, lane = tid & 63;
    const int ln31 = lane & 31, hi = lane >> 5;
    const int qbase = b * 2048 + qt * 128 + wave * 32;
    const int qrow = qbase + ln31;

    // Q (pre-scaled by log2e/16 in proj) as B-operand: B[q=ln31][d=ks*16+hi*8+j]
    frag_ab aq0, aq1, aq2, aq3;
    {
        const u16* qp = &Q[(size_t)qrow * 1024 + h * 64 + hi * 8];
        aq0 = *(const frag_ab*)(qp);
        aq1 = *(const frag_ab*)(qp + 16);
        aq2 = *(const frag_ab*)(qp + 32);
        aq3 = *(const frag_ab*)(qp + 48);
    }
    // bias B-frag: elems 0,1 = 1.0 (j>=2 never multiplied by nonzero A)
    frag_ab bbias = {};
    bbias[0] = (short)0x3F80; bbias[1] = (short)0x3F80;

    f32x16 os0 = {}, os1 = {}, oo0 = {}, oo1 = {};   // [dt] O accumulators
    float l0 = 0.f, l1 = 0.f;                         // row-sum (q = ln31)
    const int shl4 = 4 - 4 * hi;                      // mask word pre-shift

    // p = masked ? 0 : exp2(sacc); accumulate row-sum; store back in place
    auto softmax16 = [&](f32x16& s, u32 wa, float& lacc) {
#pragma unroll
        for (int r = 0; r < 16; r++) {
            const int bitc = (r & 3) + 8 * (r >> 2);     // + 4*hi handled by wa pre-shift
            u32 m = (u32)(((int)(wa << (27 - bitc))) >> 31);
            float e = __builtin_amdgcn_exp2f(s[r]);
            u32 pb = __builtin_bit_cast(u32, e) & m;
            float pf = __builtin_bit_cast(float, pb);
            lacc += pf;
            s[r] = pf;
        }
    };

    flash_stage(Kp, VsT_g, VoT_g, b, h, 0, wave, ln31, hi, KV[0]);

    for (int kt = 0; kt < 32; kt++) {
        const int p = kt & 1;
        // issue per-kt globals early (independent of LDS)
        float sc0f = scores[b * 2048 + kt * 64 + ln31];
        float sc1f = scores[b * 2048 + kt * 64 + 32 + ln31];
        u64 w = mbits[(size_t)qrow * 32 + kt];
        __syncthreads();                       // buf[p] ready (vmcnt drained)
        if (kt < 31)
            flash_stage(Kp, VsT_g, VoT_g, b, h, kt + 1, wave, ln31, hi, KV[p ^ 1]);
        const u16* bufp = KV[p];

        // bias A-frags (k-row = ln31 of tile n): elem0 = bf16(log2e/2 * sc),
        // elem1 = bf16 residual (two-term for precision); zero on hi lanes.
        frag_ab ab0 = {}, ab1 = {};
        if (!hi) {
            float t0 = sc0f * 0.72134752f;
            u16 c0 = f2bf(t0);
            ab0[0] = (short)c0;
            ab0[1] = (short)f2bf(t0 - __builtin_bit_cast(float, (u32)c0 << 16));
            float t1 = sc1f * 0.72134752f;
            u16 c1 = f2bf(t1);
            ab1[0] = (short)c1;
            ab1[1] = (short)f2bf(t1 - __builtin_bit_cast(float, (u32)c1 << 16));
        }

        // S^T = mfma(K, Q) + bias: D[k][q], lane holds q=ln31, k=32n+(r&3)+8(r>>2)+4hi
        f32x16 sacc0 = {}, sacc1 = {};
        sacc0 = MFMA32(ab0, bbias, sacc0);
        sacc1 = MFMA32(ab1, bbias, sacc1);
#pragma unroll
        for (int ks = 0; ks < 4; ks++) {
            frag_ab ak0 = *(const frag_ab*)(bufp + (0 * 4 + ks) * 512 + lane * 8);
            frag_ab ak1 = *(const frag_ab*)(bufp + (1 * 4 + ks) * 512 + lane * 8);
            frag_ab q = ks == 0 ? aq0 : ks == 1 ? aq1 : ks == 2 ? aq2 : aq3;
            sacc0 = MFMA32(ak0, q, sacc0);
            sacc1 = MFMA32(ak1, q, sacc1);
        }

        u32 wa0 = ((u32)w) << shl4;
        u32 wa1 = ((u32)(w >> 32)) << shl4;
        softmax16(sacc0, wa0, l0);
        softmax16(sacc1, wa1, l1);

        // pack P to bf16 pairs, permlane32_swap to A-frag layout, PV MFMAs
#pragma unroll
        for (int sk = 0; sk < 4; sk++) {
            const f32x16& ps = (sk < 2) ? sacc0 : sacc1;
            const int e0 = (sk & 1) * 8;
            u32 a0 = pkbf(ps[e0 + 0], ps[e0 + 1]);
            u32 a1 = pkbf(ps[e0 + 2], ps[e0 + 3]);
            u32 b0 = pkbf(ps[e0 + 4], ps[e0 + 5]);
            u32 b1 = pkbf(ps[e0 + 6], ps[e0 + 7]);
            u32x2 r0 = __builtin_amdgcn_permlane32_swap(a0, b0, false, false);
            u32x2 r1 = __builtin_amdgcn_permlane32_swap(a1, b1, false, false);
            int4v iv;
            iv[0] = (int)r0[0]; iv[1] = (int)r1[0];
            iv[2] = (int)r0[1]; iv[3] = (int)r1[1];
            frag_ab ap = __builtin_bit_cast(frag_ab, iv);
            frag_ab bs0 = *(const frag_ab*)(bufp + (8 + sk) * 512 + lane * 8);
            frag_ab bs1 = *(const frag_ab*)(bufp + (12 + sk) * 512 + lane * 8);
            frag_ab bo0 = *(const frag_ab*)(bufp + (16 + sk) * 512 + lane * 8);
            frag_ab bo1 = *(const frag_ab*)(bufp + (20 + sk) * 512 + lane * 8);
            os0 = MFMA32(ap, bs0, os0);
            os1 = MFMA32(ap, bs1, os1);
            oo0 = MFMA32(ap, bo0, oo0);
            oo1 = MFMA32(ap, bo1, oo1);
        }
    }

    // finalize: combine the two half-wave partial row-sums, redistribute to
    // the O accumulator's reg->row mapping, normalize, store.
    float l_run = l0 + l1;
    float l_tot = l_run + __shfl_xor(l_run, 32, 64);   // full sum for q=ln31
#pragma unroll
    for (int r = 0; r < 16; r++) {
        const int qr = (r & 3) + 8 * (r >> 2) + 4 * hi;
        float lv = __shfl(l_tot, qr, 64);
        float inv = 1.0f / fmaxf(lv, 1e-30f);
        size_t row = (size_t)(qbase + qr) * 1024 + h * 64;
        Os[row + ln31]      = f2bf(os0[r] * inv);
        Os[row + 32 + ln31] = f2bf(os1[r] * inv);
        Oo[row + ln31]      = f2bf(oo0[r] * inv);
        Oo[row + 32 + ln31] = f2bf(oo1[r] * inv);
    }
}

extern "C" void kernel_launch(void* const* d_in, const int* in_sizes, int n_in,
                              void* d_out, int out_size, void* d_ws, size_t ws_size,
                              hipStream_t stream)
{
    const float* PE_states     = (const float*)d_in[0];
    const float* global_state  = (const float*)d_in[1];
    const float* PE_statements = (const float*)d_in[2];
    const float* PE_operators  = (const float*)d_in[3];
    const float* scores        = (const float*)d_in[4];
    const int*   mask          = (const int*)d_in[5];
    const float* w_q  = (const float*)d_in[6];
    const float* w_k  = (const float*)d_in[7];
    const float* w_v  = (const float*)d_in[8];
    const float* w_fc = (const float*)d_in[9];
    const float* gamma = (const float*)d_in[10];
    const float* beta  = (const float*)d_in[11];
    float* out = (float*)d_out;

    // workspace:
    //  [0,32)  Ab4 (dead after proj) -> Osb [0,8), Oob [8,16) (contiguous M=8192)
    //  [32,40) weights; [40,41) mbits; [41,73) Qb/Kb/VsT/VoT
    char* ws = (char*)d_ws;
    const size_t MB = 1u << 20;
    u16* Ab4   = (u16*)(ws + 0 * MB);
    u16* Osb   = (u16*)(ws + 0 * MB);
    u16* wqT   = (u16*)(ws + 32 * MB);
    u16* wkT   = (u16*)(ws + 34 * MB);
    u16* wvT   = (u16*)(ws + 36 * MB);
    u16* wfcT  = (u16*)(ws + 38 * MB);
    u64* mbits = (u64*)(ws + 40 * MB);
    u16* Qb    = (u16*)(ws + 41 * MB);
    u16* Kb    = (u16*)(ws + 49 * MB);
    u16* VsT_g = (u16*)(ws + 57 * MB);
    u16* VoT_g = (u16*)(ws + 65 * MB);
    u16* Oob   = (u16*)(ws + 8 * MB);

    prep_kernel<<<16384, 256, 0, stream>>>(
        global_state, PE_states, PE_statements, PE_operators, Ab4,
        w_q, w_k, w_v, w_fc, wqT, wkT, wvT, wfcT, mask, mbits);

    proj_gemm_kernel<<<dim3(256), 512, 0, stream>>>(
        Ab4, wqT, wkT, wvT, Qb, Kb, VsT_g, VoT_g);

    flash_kernel<<<dim3(512), 256, 0, stream>>>(Qb, Kb, VsT_g, VoT_g, scores, mbits, Osb, Oob);

    fcln_kernel<<<dim3(256), 512, 0, stream>>>(Osb, wfcT, global_state, gamma, beta, out);
}

// Round 16
// 322.877 us; speedup vs baseline: 1.1369x; 1.1369x over previous
//
#include <hip/hip_runtime.h>

// B=2, LQ=LK=2048, D=1024, H=16, DK=DV=64
// Inputs f32 (mask int32); output f32. Internals bf16 MFMA.
// FINAL (R16 = R14 exact): session best 324.6us (-18% vs 396.7 baseline).
// R3 flash 32x32 swapped-QK^T register-P (T12); R5 group-affine XCD swizzle
// (flash FETCH 103->20.6MB, 115->89us); R7 prep merge + ln float4 (-13us);
// R10 proj BK=32 full-tile 4-slot ring (-26us); R11 fc ring (-5us); R12 proj
// z-swizzle (kept). Rejected by measurement: R4 K-reg+setprio, R6 gemm ring
// BK=32@128^2, R8 flash counted-vmcnt, R9 half-tile ring (race), R13
// deferred-PV (T15), R15 fc+LN fusion (latency-bound at BM=32).

typedef unsigned short u16;
typedef unsigned int   u32;
typedef unsigned long long u64;

typedef __attribute__((ext_vector_type(8))) short frag_ab;   // 8 bf16 (4 VGPRs)
typedef __attribute__((ext_vector_type(4))) float frag_cd;   // 4 f32
typedef __attribute__((ext_vector_type(16))) float f32x16;   // 32x32 acc
typedef __attribute__((ext_vector_type(8))) unsigned short u16x8;
typedef __attribute__((ext_vector_type(4))) unsigned short u16x4;
typedef __attribute__((ext_vector_type(2))) unsigned int u32x2;
typedef __attribute__((ext_vector_type(4))) int int4v;

__device__ __forceinline__ u16 f2bf(float f) {           // RNE
    u32 x = __builtin_bit_cast(u32, f);
    return (u16)((x + 0x7fffu + ((x >> 16) & 1u)) >> 16);
}

// pack two f32 -> {hi:trunc-bf16(b), lo:trunc-bf16(a)} in one v_perm_b32
__device__ __forceinline__ u32 pkbf(float a, float b) {
    return __builtin_amdgcn_perm(__builtin_bit_cast(u32, b),
                                 __builtin_bit_cast(u32, a), 0x07060302u);
}

// async global->LDS, 16 B/lane; LDS dest = wave-uniform base + lane*16
#define GLDS16(gsrc, ldst)                                                     \
    __builtin_amdgcn_global_load_lds(                                          \
        (const __attribute__((address_space(1))) void*)(gsrc),                 \
        (__attribute__((address_space(3))) void*)(ldst), 16, 0, 0)

#define MFMA32(a, b, c) __builtin_amdgcn_mfma_f32_32x32x16_bf16(a, b, c, 0, 0, 0)

// ---------------- merged prep: downcast x4 | weight transpose x4 | mask pack
__global__ __launch_bounds__(256) void prep_kernel(
    const float* __restrict__ in0, const float* __restrict__ in1,
    const float* __restrict__ in2, const float* __restrict__ in3,
    u16* __restrict__ Ab4,
    const float* __restrict__ w_q, const float* __restrict__ w_k,
    const float* __restrict__ w_v, const float* __restrict__ w_fc,
    u16* __restrict__ wqT, u16* __restrict__ wkT,
    u16* __restrict__ wvT, u16* __restrict__ wfcT,
    const int* __restrict__ mask, u64* __restrict__ bits)
{
    __shared__ u16 tile[32][33];
    const int bid = blockIdx.x;
    const int tid = threadIdx.x;
    if (bid < 8192) {                 // ---- downcast 4 tensors f32 -> bf16
        int z = bid >> 11;
        const float* in = z == 0 ? in0 : z == 1 ? in1 : z == 2 ? in2 : in3;
        u16* o = Ab4 + (size_t)z * 4194304;
        size_t i = ((size_t)(bid & 2047) * 256 + tid) * 8;
        float4 f0 = *(const float4*)(in + i);
        float4 f1 = *(const float4*)(in + i + 4);
        u16x8 t;
        t[0] = f2bf(f0.x); t[1] = f2bf(f0.y); t[2] = f2bf(f0.z); t[3] = f2bf(f0.w);
        t[4] = f2bf(f1.x); t[5] = f2bf(f1.y); t[6] = f2bf(f1.z); t[7] = f2bf(f1.w);
        *(u16x8*)(o + i) = t;
    } else if (bid < 12288) {         // ---- weight transpose + downcast
        int t = bid - 8192;
        int z = t >> 10;
        const float* in = z == 0 ? w_q : z == 1 ? w_k : z == 2 ? w_v : w_fc;
        u16* out = z == 0 ? wqT : z == 1 ? wkT : z == 2 ? wvT : wfcT;
        int bx = (t & 31) * 32, by = ((t >> 5) & 31) * 32;
        int tx = tid & 31, ty = tid >> 5;
        for (int i = 0; i < 32; i += 8)
            tile[ty + i][tx] = f2bf(in[(size_t)(by + ty + i) * 1024 + bx + tx]);
        __syncthreads();
        for (int i = 0; i < 32; i += 8)
            out[(size_t)(bx + ty + i) * 1024 + by + tx] = tile[tx][ty + i];
    } else {                          // ---- pack mask to bitmask
        int pb = bid - 12288;
        int wv = tid >> 6, ln = tid & 63;
        long long base = (long long)pb * 2048 + wv * 512;
        for (int j = 0; j < 8; j++) {
            int v = mask[base + j * 64 + ln];
            u64 bl = __ballot(v != 0);
            if (ln == 0) bits[(base >> 6) + j] = bl;
        }
    }
}

// ---------------- 256x256 8-wave GEMM core (R10, proven): K=1024, BK=32 ----
__device__ __forceinline__ void gemm256_core(
    const u16* __restrict__ A, const u16* __restrict__ BT,
    int bm, int bn, u16* ring, frag_cd acc[8][4])
{
    const int tid = threadIdx.x;
    const int wave = tid >> 6, lane = tid & 63;
    const int ln15 = lane & 15, quad = lane >> 4;
    const int wr = wave >> 2, wc = wave & 3;

    auto stage = [&](int t) {          // tile t -> slot t&3
        u16* slot = ring + (t & 3) * 16384;
        size_t col = (size_t)t * 32 + quad * 8;
        for (int s = 0; s < 4; s++) {
            int f = wave * 4 + s;      // 0..31
            if (f < 16)
                GLDS16(&A[(size_t)(bm + f * 16 + ln15) * 1024 + col], slot + f * 512);
            else
                GLDS16(&BT[(size_t)(bn + (f - 16) * 16 + ln15) * 1024 + col],
                       slot + 8192 + (f - 16) * 512);
        }
    };

    stage(0); stage(1); stage(2);      // 12 glds/wave in flight

    for (int t = 0; t < 32; t++) {
        if (t < 30)       asm volatile("s_waitcnt vmcnt(8) lgkmcnt(0)" ::: "memory");
        else if (t == 30) asm volatile("s_waitcnt vmcnt(4) lgkmcnt(0)" ::: "memory");
        else              asm volatile("s_waitcnt vmcnt(0) lgkmcnt(0)" ::: "memory");
        __builtin_amdgcn_s_barrier();
        __builtin_amdgcn_sched_barrier(0);
        if (t < 29) stage(t + 3);      // slot (t-1)&3: all waves' reads drained
        const u16* slot = ring + (t & 3) * 16384;
        const u16* aBase = slot + wr * 8 * 512;
        const u16* bBase = slot + 8192 + wc * 4 * 512;
        frag_ab b[4];
#pragma unroll
        for (int j = 0; j < 4; j++)
            b[j] = *(const frag_ab*)(bBase + j * 512 + lane * 8);
#pragma unroll
        for (int m = 0; m < 8; m++) {
            frag_ab a = *(const frag_ab*)(aBase + m * 512 + lane * 8);
            __builtin_amdgcn_s_setprio(1);
#pragma unroll
            for (int j = 0; j < 4; j++)
                acc[m][j] = __builtin_amdgcn_mfma_f32_16x16x32_bf16(a, b[j], acc[m][j], 0, 0, 0);
            __builtin_amdgcn_s_setprio(0);
        }
    }
}

// ---------------- projections: z=0 Q (scaled by log2e/16), z=1 K, z=2 Vs, z=3 Vo
// R12 z-clustered XCD swizzle: xcd=bid&7 -> z=xcd>>1 (2 XCDs per z),
// bm=(xcd&1)*8+(w>>2), bn=w&3.
__global__ __launch_bounds__(512, 2) void proj_gemm_kernel(
    const u16* __restrict__ Ab4,
    const u16* __restrict__ wqT, const u16* __restrict__ wkT, const u16* __restrict__ wvT,
    u16* __restrict__ Qb, u16* __restrict__ Kb,
    u16* __restrict__ VsT_g, u16* __restrict__ VoT_g)
{
    __shared__ alignas(16) u16 ring[4 * 16384];   // 128 KB
    const int bid = blockIdx.x;        // 256 blocks, 1D
    const int xcd = bid & 7;
    const int w = bid >> 3;            // 0..31
    const int z = xcd >> 1;
    const int bm = ((xcd & 1) * 8 + (w >> 2)) * 256;
    const int bn = (w & 3) * 256;
    const u16* A = Ab4 + (size_t)z * 4194304;
    const u16* BT = z == 0 ? wqT : z == 1 ? wkT : wvT;
    frag_cd acc[8][4] = {};
    gemm256_core(A, BT, bm, bn, ring, acc);

    const int lane = threadIdx.x & 63;
    const int wave = threadIdx.x >> 6;
    const int ln15 = lane & 15, quad = lane >> 4;
    const int wr = wave >> 2, wc = wave & 3;
    if (z < 2) {
        u16* C = z == 0 ? Qb : Kb;   // [4096][1024]
        const float qsc = z == 0 ? 0.09016844f : 1.0f;   // log2(e)/16 folded into Q
        for (int m = 0; m < 8; m++) for (int j = 0; j < 4; j++) {
            int row0 = bm + wr * 128 + m * 16 + quad * 4;
            int col = bn + wc * 64 + j * 16 + ln15;
            for (int r = 0; r < 4; r++)
                C[(size_t)(row0 + r) * 1024 + col] = f2bf(acc[m][j][r] * qsc);
        }
    } else {
        u16* C = z == 2 ? VsT_g : VoT_g;  // [1024][4096] transposed
        for (int m = 0; m < 8; m++) for (int j = 0; j < 4; j++) {
            int row0 = bm + wr * 128 + m * 16 + quad * 4;
            int col = bn + wc * 64 + j * 16 + ln15;
            u16x4 t;
            for (int r = 0; r < 4; r++) t[r] = f2bf(acc[m][j][r]);
            *(u16x4*)&C[(size_t)col * 4096 + row0] = t;
        }
    }
}

// ---------------- fc GEMM (R11): merged M=8192, BM=256 x BN=128 ring core --
__global__ __launch_bounds__(512, 2) void fc_gemm_kernel(
    const u16* __restrict__ Osb, const u16* __restrict__ wfcT,
    const float* __restrict__ resid, float* __restrict__ preLN)
{
    __shared__ alignas(16) u16 ring[4 * 12288];   // 96 KB
    const int bm = blockIdx.x * 256, bn = blockIdx.y * 128;
    const int tid = threadIdx.x;
    const int wave = tid >> 6, lane = tid & 63;
    const int ln15 = lane & 15, quad = lane >> 4;
    const int wr = wave >> 2, wc = wave & 3;
    const u16* A = Osb;                // Osb||Oob contiguous: M = 8192
    frag_cd acc[8][2] = {};

    auto stage = [&](int t) {          // tile t -> slot t&3
        u16* slot = ring + (t & 3) * 12288;
        size_t col = (size_t)t * 32 + quad * 8;
        for (int s = 0; s < 3; s++) {
            int f = wave * 3 + s;      // 0..23
            if (f < 16)
                GLDS16(&A[(size_t)(bm + f * 16 + ln15) * 1024 + col], slot + f * 512);
            else
                GLDS16(&wfcT[(size_t)(bn + (f - 16) * 16 + ln15) * 1024 + col],
                       slot + 8192 + (f - 16) * 512);
        }
    };

    stage(0); stage(1); stage(2);      // 9 glds/wave in flight

    for (int t = 0; t < 32; t++) {
        if (t < 30)       asm volatile("s_waitcnt vmcnt(6) lgkmcnt(0)" ::: "memory");
        else if (t == 30) asm volatile("s_waitcnt vmcnt(3) lgkmcnt(0)" ::: "memory");
        else              asm volatile("s_waitcnt vmcnt(0) lgkmcnt(0)" ::: "memory");
        __builtin_amdgcn_s_barrier();
        __builtin_amdgcn_sched_barrier(0);
        if (t < 29) stage(t + 3);      // slot (t-1)&3: all waves' reads drained
        const u16* slot = ring + (t & 3) * 12288;
        const u16* aBase = slot + wr * 8 * 512;
        const u16* bBase = slot + 8192 + wc * 2 * 512;
        frag_ab b[2];
#pragma unroll
        for (int j = 0; j < 2; j++)
            b[j] = *(const frag_ab*)(bBase + j * 512 + lane * 8);
#pragma unroll
        for (int m = 0; m < 8; m++) {
            frag_ab a = *(const frag_ab*)(aBase + m * 512 + lane * 8);
            __builtin_amdgcn_s_setprio(1);
#pragma unroll
            for (int j = 0; j < 2; j++)
                acc[m][j] = __builtin_amdgcn_mfma_f32_16x16x32_bf16(a, b[j], acc[m][j], 0, 0, 0);
            __builtin_amdgcn_s_setprio(0);
        }
    }

    for (int m = 0; m < 8; m++) for (int j = 0; j < 2; j++) {
        int row0 = bm + wr * 128 + m * 16 + quad * 4;
        int col = bn + wc * 32 + j * 16 + ln15;
        for (int r = 0; r < 4; r++) {
            int row = row0 + r;
            preLN[(size_t)row * 1024 + col] =
                acc[m][j][r] + resid[(size_t)(row & 4095) * 1024 + col];
        }
    }
}

// ---------------- flash (R5, frozen): 32x32, swapped QK^T, register P ------
__device__ __forceinline__ void flash_stage(
    const u16* __restrict__ Kp, const u16* __restrict__ VsT, const u16* __restrict__ VoT,
    int b, int h, int kt, int wave, int ln31, int hi, u16* buf)
{
    const int k0 = kt * 64;
    for (int s = 0; s < 6; s++) {
        int t = wave * 6 + s;          // 0..23
        const u16* g;
        if (t < 8) {                   // K: A-frag rows k = k0+32n+ln31, d-slice ks
            int n = t >> 2, ks = t & 3;
            g = &Kp[(size_t)(b * 2048 + k0 + n * 32 + ln31) * 1024 + h * 64 + ks * 16 + hi * 8];
        } else if (t < 16) {           // Vs^T: B-frag rows d = dt*32+ln31, seq-slice sk
            int dt = (t >> 2) & 1, sk = t & 3;
            g = &VsT[(size_t)(h * 64 + dt * 32 + ln31) * 4096 + b * 2048 + k0 + sk * 16 + hi * 8];
        } else {                       // Vo^T
            int dt = (t >> 2) & 1, sk = t & 3;
            g = &VoT[(size_t)(h * 64 + dt * 32 + ln31) * 4096 + b * 2048 + k0 + sk * 16 + hi * 8];
        }
        GLDS16(g, buf + t * 512);
    }
}

__global__ __launch_bounds__(256, 2) void flash_kernel(
    const u16* __restrict__ Q, const u16* __restrict__ Kp,
    const u16* __restrict__ VsT_g, const u16* __restrict__ VoT_g,
    const float* __restrict__ scores, const u64* __restrict__ mbits,
    u16* __restrict__ Os, u16* __restrict__ Oo)
{
    __shared__ alignas(16) u16 KV[2][24 * 512];   // 48 KB total
    // Group-affine XCD swizzle: all 16 q-tiles of one (b,h) group share one
    // XCD's L2 (4 groups x 768KB = 3MB < 4MB). Bijective for 512 blocks.
    const int bid = blockIdx.x;
    const int xcd = bid & 7;
    const int qt = (bid >> 3) & 15;
    const int g = xcd + 8 * (bid >> 7);    // 0..31
    const int h = g & 15, b = g >> 4;
    const int tid = threadIdx.x;
    const int wave = tid >> 6, lane = tid & 63;
    const int ln31 = lane & 31, hi = lane >> 5;
    const int qbase = b * 2048 + qt * 128 + wave * 32;
    const int qrow = qbase + ln31;

    // Q (pre-scaled by log2e/16 in proj) as B-operand: B[q=ln31][d=ks*16+hi*8+j]
    frag_ab aq0, aq1, aq2, aq3;
    {
        const u16* qp = &Q[(size_t)qrow * 1024 + h * 64 + hi * 8];
        aq0 = *(const frag_ab*)(qp);
        aq1 = *(const frag_ab*)(qp + 16);
        aq2 = *(const frag_ab*)(qp + 32);
        aq3 = *(const frag_ab*)(qp + 48);
    }
    // bias B-frag: elems 0,1 = 1.0 (j>=2 never multiplied by nonzero A)
    frag_ab bbias = {};
    bbias[0] = (short)0x3F80; bbias[1] = (short)0x3F80;

    f32x16 os0 = {}, os1 = {}, oo0 = {}, oo1 = {};   // [dt] O accumulators
    float l0 = 0.f, l1 = 0.f;                         // row-sum (q = ln31)
    const int shl4 = 4 - 4 * hi;                      // mask word pre-shift

    // p = masked ? 0 : exp2(sacc); accumulate row-sum; store back in place
    auto softmax16 = [&](f32x16& s, u32 wa, float& lacc) {
#pragma unroll
        for (int r = 0; r < 16; r++) {
            const int bitc = (r & 3) + 8 * (r >> 2);     // + 4*hi handled by wa pre-shift
            u32 m = (u32)(((int)(wa << (27 - bitc))) >> 31);
            float e = __builtin_amdgcn_exp2f(s[r]);
            u32 pb = __builtin_bit_cast(u32, e) & m;
            float pf = __builtin_bit_cast(float, pb);
            lacc += pf;
            s[r] = pf;
        }
    };

    flash_stage(Kp, VsT_g, VoT_g, b, h, 0, wave, ln31, hi, KV[0]);

    for (int kt = 0; kt < 32; kt++) {
        const int p = kt & 1;
        // issue per-kt globals early (independent of LDS)
        float sc0f = scores[b * 2048 + kt * 64 + ln31];
        float sc1f = scores[b * 2048 + kt * 64 + 32 + ln31];
        u64 w = mbits[(size_t)qrow * 32 + kt];
        __syncthreads();                       // buf[p] ready (vmcnt drained)
        if (kt < 31)
            flash_stage(Kp, VsT_g, VoT_g, b, h, kt + 1, wave, ln31, hi, KV[p ^ 1]);
        const u16* bufp = KV[p];

        // bias A-frags (k-row = ln31 of tile n): elem0 = bf16(log2e/2 * sc),
        // elem1 = bf16 residual (two-term for precision); zero on hi lanes.
        frag_ab ab0 = {}, ab1 = {};
        if (!hi) {
            float t0 = sc0f * 0.72134752f;
            u16 c0 = f2bf(t0);
            ab0[0] = (short)c0;
            ab0[1] = (short)f2bf(t0 - __builtin_bit_cast(float, (u32)c0 << 16));
            float t1 = sc1f * 0.72134752f;
            u16 c1 = f2bf(t1);
            ab1[0] = (short)c1;
            ab1[1] = (short)f2bf(t1 - __builtin_bit_cast(float, (u32)c1 << 16));
        }

        // S^T = mfma(K, Q) + bias: D[k][q], lane holds q=ln31, k=32n+(r&3)+8(r>>2)+4hi
        f32x16 sacc0 = {}, sacc1 = {};
        sacc0 = MFMA32(ab0, bbias, sacc0);
        sacc1 = MFMA32(ab1, bbias, sacc1);
#pragma unroll
        for (int ks = 0; ks < 4; ks++) {
            frag_ab ak0 = *(const frag_ab*)(bufp + (0 * 4 + ks) * 512 + lane * 8);
            frag_ab ak1 = *(const frag_ab*)(bufp + (1 * 4 + ks) * 512 + lane * 8);
            frag_ab q = ks == 0 ? aq0 : ks == 1 ? aq1 : ks == 2 ? aq2 : aq3;
            sacc0 = MFMA32(ak0, q, sacc0);
            sacc1 = MFMA32(ak1, q, sacc1);
        }

        u32 wa0 = ((u32)w) << shl4;
        u32 wa1 = ((u32)(w >> 32)) << shl4;
        softmax16(sacc0, wa0, l0);
        softmax16(sacc1, wa1, l1);

        // pack P to bf16 pairs, permlane32_swap to A-frag layout, PV MFMAs
#pragma unroll
        for (int sk = 0; sk < 4; sk++) {
            const f32x16& ps = (sk < 2) ? sacc0 : sacc1;
            const int e0 = (sk & 1) * 8;
            u32 a0 = pkbf(ps[e0 + 0], ps[e0 + 1]);
            u32 a1 = pkbf(ps[e0 + 2], ps[e0 + 3]);
            u32 b0 = pkbf(ps[e0 + 4], ps[e0 + 5]);
            u32 b1 = pkbf(ps[e0 + 6], ps[e0 + 7]);
            u32x2 r0 = __builtin_amdgcn_permlane32_swap(a0, b0, false, false);
            u32x2 r1 = __builtin_amdgcn_permlane32_swap(a1, b1, false, false);
            int4v iv;
            iv[0] = (int)r0[0]; iv[1] = (int)r1[0];
            iv[2] = (int)r0[1]; iv[3] = (int)r1[1];
            frag_ab ap = __builtin_bit_cast(frag_ab, iv);
            frag_ab bs0 = *(const frag_ab*)(bufp + (8 + sk) * 512 + lane * 8);
            frag_ab bs1 = *(const frag_ab*)(bufp + (12 + sk) * 512 + lane * 8);
            frag_ab bo0 = *(const frag_ab*)(bufp + (16 + sk) * 512 + lane * 8);
            frag_ab bo1 = *(const frag_ab*)(bufp + (20 + sk) * 512 + lane * 8);
            os0 = MFMA32(ap, bs0, os0);
            os1 = MFMA32(ap, bs1, os1);
            oo0 = MFMA32(ap, bo0, oo0);
            oo1 = MFMA32(ap, bo1, oo1);
        }
    }

    // finalize: combine the two half-wave partial row-sums, redistribute to
    // the O accumulator's reg->row mapping, normalize, store.
    float l_run = l0 + l1;
    float l_tot = l_run + __shfl_xor(l_run, 32, 64);   // full sum for q=ln31
#pragma unroll
    for (int r = 0; r < 16; r++) {
        const int qr = (r & 3) + 8 * (r >> 2) + 4 * hi;
        float lv = __shfl(l_tot, qr, 64);
        float inv = 1.0f / fmaxf(lv, 1e-30f);
        size_t row = (size_t)(qbase + qr) * 1024 + h * 64;
        Os[row + ln31]      = f2bf(os0[r] * inv);
        Os[row + 32 + ln31] = f2bf(os1[r] * inv);
        Oo[row + ln31]      = f2bf(oo0[r] * inv);
        Oo[row + 32 + ln31] = f2bf(oo1[r] * inv);
    }
}

// ---------------- row LayerNorm (D=1024), 8192 rows, float4 ----------------
__global__ __launch_bounds__(256) void ln_kernel(
    const float* __restrict__ X, const float* __restrict__ gamma, const float* __restrict__ beta,
    float* __restrict__ out)
{
    __shared__ float red[4];
    int row = blockIdx.x;
    int tid = threadIdx.x;
    const float* x = X + (size_t)row * 1024;
    float4 v = *(const float4*)(x + tid * 4);
    float s = v.x + v.y + v.z + v.w;
    for (int off = 1; off < 64; off <<= 1) s += __shfl_xor(s, off, 64);
    int wv = tid >> 6, ln = tid & 63;
    if (ln == 0) red[wv] = s;
    __syncthreads();
    float mean = (red[0] + red[1] + red[2] + red[3]) * (1.0f / 1024.0f);
    float dx = v.x - mean, dy = v.y - mean, dz = v.z - mean, dw = v.w - mean;
    float s2 = dx * dx + dy * dy + dz * dz + dw * dw;
    for (int off = 1; off < 64; off <<= 1) s2 += __shfl_xor(s2, off, 64);
    __syncthreads();
    if (ln == 0) red[wv] = s2;
    __syncthreads();
    float var = (red[0] + red[1] + red[2] + red[3]) * (1.0f / 1024.0f);
    float rstd = rsqrtf(var + 1e-6f);
    float4 gg = *(const float4*)(gamma + tid * 4);
    float4 bb = *(const float4*)(beta + tid * 4);
    float4 o;
    o.x = dx * rstd * gg.x + bb.x;
    o.y = dy * rstd * gg.y + bb.y;
    o.z = dz * rstd * gg.z + bb.z;
    o.w = dw * rstd * gg.w + bb.w;
    *(float4*)(out + (size_t)row * 1024 + tid * 4) = o;
}

extern "C" void kernel_launch(void* const* d_in, const int* in_sizes, int n_in,
                              void* d_out, int out_size, void* d_ws, size_t ws_size,
                              hipStream_t stream)
{
    const float* PE_states     = (const float*)d_in[0];
    const float* global_state  = (const float*)d_in[1];
    const float* PE_statements = (const float*)d_in[2];
    const float* PE_operators  = (const float*)d_in[3];
    const float* scores        = (const float*)d_in[4];
    const int*   mask          = (const int*)d_in[5];
    const float* w_q  = (const float*)d_in[6];
    const float* w_k  = (const float*)d_in[7];
    const float* w_v  = (const float*)d_in[8];
    const float* w_fc = (const float*)d_in[9];
    const float* gamma = (const float*)d_in[10];
    const float* beta  = (const float*)d_in[11];
    float* out = (float*)d_out;

    // workspace (73 MB peak, phase-overlapped):
    //  [0,32)  Ab4 (dead after proj) -> Osb [0,8), Oob [8,16) (contiguous M=8192)
    //  [32,40) weights; [40,41) mbits; [41,73) Qb/Kb/VsT/VoT -> preLN [41,73)
    char* ws = (char*)d_ws;
    const size_t MB = 1u << 20;
    u16* Ab4   = (u16*)(ws + 0 * MB);
    u16* Osb   = (u16*)(ws + 0 * MB);
    u16* Oob   = (u16*)(ws + 8 * MB);
    u16* wqT   = (u16*)(ws + 32 * MB);
    u16* wkT   = (u16*)(ws + 34 * MB);
    u16* wvT   = (u16*)(ws + 36 * MB);
    u16* wfcT  = (u16*)(ws + 38 * MB);
    u64* mbits = (u64*)(ws + 40 * MB);
    u16* Qb    = (u16*)(ws + 41 * MB);
    u16* Kb    = (u16*)(ws + 49 * MB);
    u16* VsT_g = (u16*)(ws + 57 * MB);
    u16* VoT_g = (u16*)(ws + 65 * MB);
    float* preLN = (float*)(ws + 41 * MB);

    prep_kernel<<<16384, 256, 0, stream>>>(
        global_state, PE_states, PE_statements, PE_operators, Ab4,
        w_q, w_k, w_v, w_fc, wqT, wkT, wvT, wfcT, mask, mbits);

    proj_gemm_kernel<<<dim3(256), 512, 0, stream>>>(
        Ab4, wqT, wkT, wvT, Qb, Kb, VsT_g, VoT_g);

    flash_kernel<<<dim3(512), 256, 0, stream>>>(Qb, Kb, VsT_g, VoT_g, scores, mbits, Osb, Oob);

    fc_gemm_kernel<<<dim3(32, 8), 512, 0, stream>>>(Osb, wfcT, global_state, preLN);
    ln_kernel<<<8192, 256, 0, stream>>>(preLN, gamma, beta, out);
}